// Round 13
// baseline (409.392 us; speedup 1.0000x reference)
//
#include <hip/hip_runtime.h>
#include <hip/hip_bf16.h>
#include <math.h>

#define DIM 128

typedef __attribute__((ext_vector_type(8))) short bf16x8;
typedef __attribute__((ext_vector_type(4))) float f32x4;

__device__ __forceinline__ ushort f2bf(float f) {  // RTNE
  unsigned u = __float_as_uint(f);
  return (ushort)((u + 0x7FFFu + ((u >> 16) & 1u)) >> 16);
}
__device__ __forceinline__ float bf2f(ushort h) {
  return __uint_as_float(((unsigned)h) << 16);
}

// ---------------- fused prep: hist_rank || cast || wsplit, INTERLEAVED ----------------
__global__ __launch_bounds__(256) void prep_kernel(
    const int* __restrict__ dst, unsigned* __restrict__ deg, unsigned* __restrict__ rank, int E,
    const float* __restrict__ x, ushort* __restrict__ xh, long total,
    const float* __restrict__ W1l, const float* __restrict__ W1r,
    const float* __restrict__ W2l, const float* __restrict__ W2r,
    ushort* __restrict__ tabs, int H, int C) {
  const int bid = blockIdx.x;
  const int r = bid % 3;
  const int q = bid / 3;
  if (r == 0) {
    if (q < H) {
      int gid = q * 256 + threadIdx.x;
      if (gid < E) rank[gid] = atomicAdd(&deg[dst[gid]], 1u);
    }
    return;
  }
  int id2 = q * 2 + (r - 1);
  if (id2 < C) {
    long i = ((long)id2 * 256 + threadIdx.x) * 4;
    if (i >= total) return;
    float4 v = *(const float4*)(x + i);
    uint2 Hh;
    Hh.x = (unsigned)f2bf(v.x) | ((unsigned)f2bf(v.y) << 16);
    Hh.y = (unsigned)f2bf(v.z) | ((unsigned)f2bf(v.w) << 16);
    *(uint2*)(xh + i) = Hh;
    return;
  }
  id2 -= C;
  if (id2 >= 256) return;
  // wsplit role: transpose + bf16 cast (hi only)
  int m = id2 >> 6;
  const float* W = (m == 0) ? W1l : (m == 1) ? W1r : (m == 2) ? W2l : W2r;
  ushort* Ht = tabs + (size_t)m * 16384;
  int idx = (id2 & 63) * 256 + threadIdx.x;  // 0..16383
  int k = idx >> 7, n = idx & 127;
  Ht[n * DIM + k] = f2bf(W[idx]);
}

// ---------------- fused scan: per-block scan + dinv; LAST block scans partials ----------------
// Last-block-ticket pattern: partials written + device fence + atomic ticket; the final
// block to arrive re-scans partial[] in-LDS (exactly the old scan_partials kernel).
__global__ __launch_bounds__(256) void scan_fused_kernel(const unsigned* __restrict__ deg,
                                                         unsigned* __restrict__ excl,
                                                         unsigned* __restrict__ partial,
                                                         float* __restrict__ dinv,
                                                         unsigned* __restrict__ ticket,
                                                         int N, int B) {
  __shared__ unsigned s[256];
  __shared__ unsigned carry;
  __shared__ int is_last;
  int i = blockIdx.x * 256 + threadIdx.x;
  unsigned v = (i < N) ? deg[i] : 0u;
  if (i < N) dinv[i] = 1.0f / fmaxf((float)v, 1.0f);
  s[threadIdx.x] = v;
  __syncthreads();
#pragma unroll
  for (int d = 1; d < 256; d <<= 1) {
    unsigned t = (threadIdx.x >= d) ? s[threadIdx.x - d] : 0u;
    __syncthreads();
    s[threadIdx.x] += t;
    __syncthreads();
  }
  if (i < N) excl[i] = s[threadIdx.x] - v;
  if (threadIdx.x == 255) partial[blockIdx.x] = s[255];

  // ticket: last block to finish scans the partials
  __threadfence();
  if (threadIdx.x == 0) is_last = (atomicAdd(ticket, 1u) == (unsigned)(B - 1));
  __syncthreads();
  if (!is_last) return;
  __threadfence();  // acquire all partials

  if (threadIdx.x == 0) carry = 0u;
  __syncthreads();
  for (int base = 0; base < B; base += 256) {
    int j = base + threadIdx.x;
    unsigned p = (j < B) ? partial[j] : 0u;
    s[threadIdx.x] = p;
    __syncthreads();
#pragma unroll
    for (int d = 1; d < 256; d <<= 1) {
      unsigned t = (threadIdx.x >= d) ? s[threadIdx.x - d] : 0u;
      __syncthreads();
      s[threadIdx.x] += t;
      __syncthreads();
    }
    if (j < B) partial[j] = carry + s[threadIdx.x] - p;
    __syncthreads();
    if (threadIdx.x == 0) carry += s[255];
    __syncthreads();
  }
}

// ---------------- CSR fill: atomic-free, offsets inline (no off[] array) ----------------
__global__ __launch_bounds__(256) void csr_fill_kernel(const int* __restrict__ src,
                                                       const int* __restrict__ dst,
                                                       const unsigned* __restrict__ rank,
                                                       const unsigned* __restrict__ excl,
                                                       const unsigned* __restrict__ partial,
                                                       int* __restrict__ csr_src, int E) {
  int e = blockIdx.x * 256 + threadIdx.x;
  if (e >= E) return;
  int d = dst[e];
  csr_src[excl[d] + partial[d >> 8] + rank[e]] = src[e];
}

// ---------------- wave-per-node gather-aggregate (offsets inline via excl/partial/deg) ----------------
__global__ __launch_bounds__(256) void gather_wave_kernel(
    const ushort* __restrict__ featH, const int* __restrict__ csr_src,
    const unsigned* __restrict__ excl, const unsigned* __restrict__ partial,
    const unsigned* __restrict__ deg, const float* __restrict__ dinv,
    ushort* __restrict__ aggH, int N) {
  const int node = (blockIdx.x * 256 + threadIdx.x) >> 6;
  if (node >= N) return;
  const int lane = threadIdx.x & 63;
  const int eslot = lane >> 4;
  const int col = lane & 15;
  const unsigned beg = excl[node] + partial[node >> 8];
  const unsigned end = beg + deg[node];
  const ushort* fbase = featH + col * 8;

  float acc[8];
#pragma unroll
  for (int t = 0; t < 8; ++t) acc[t] = 0.f;

  auto accum = [&](int4 v) {
    unsigned w0 = (unsigned)v.x, w1 = (unsigned)v.y, w2 = (unsigned)v.z, w3 = (unsigned)v.w;
    acc[0] += __uint_as_float(w0 << 16);
    acc[1] += __uint_as_float(w0 & 0xFFFF0000u);
    acc[2] += __uint_as_float(w1 << 16);
    acc[3] += __uint_as_float(w1 & 0xFFFF0000u);
    acc[4] += __uint_as_float(w2 << 16);
    acc[5] += __uint_as_float(w2 & 0xFFFF0000u);
    acc[6] += __uint_as_float(w3 << 16);
    acc[7] += __uint_as_float(w3 & 0xFFFF0000u);
  };

  unsigned base = beg;
  for (; base + 16 <= end; base += 16) {
    int s0 = csr_src[base + eslot];
    int s1 = csr_src[base + 4 + eslot];
    int s2 = csr_src[base + 8 + eslot];
    int s3 = csr_src[base + 12 + eslot];
    int4 v0 = *(const int4*)(fbase + (size_t)s0 * DIM);
    int4 v1 = *(const int4*)(fbase + (size_t)s1 * DIM);
    int4 v2 = *(const int4*)(fbase + (size_t)s2 * DIM);
    int4 v3 = *(const int4*)(fbase + (size_t)s3 * DIM);
    accum(v0); accum(v1); accum(v2); accum(v3);
  }
  for (; base + 8 <= end; base += 8) {
    int s0 = csr_src[base + eslot];
    int s1 = csr_src[base + 4 + eslot];
    int4 v0 = *(const int4*)(fbase + (size_t)s0 * DIM);
    int4 v1 = *(const int4*)(fbase + (size_t)s1 * DIM);
    accum(v0); accum(v1);
  }
  for (unsigned e = base + eslot; e < end; e += 4) {
    int s = csr_src[e];
    int4 v = *(const int4*)(fbase + (size_t)s * DIM);
    accum(v);
  }

#pragma unroll
  for (int t = 0; t < 8; ++t) {
    acc[t] += __shfl_xor(acc[t], 32, 64);
    acc[t] += __shfl_xor(acc[t], 16, 64);
  }

  if (eslot == 0) {
    float di = dinv[node];
    unsigned ph[4];
#pragma unroll
    for (int t = 0; t < 4; ++t) {
      ph[t] = (unsigned)f2bf(acc[2 * t] * di) | ((unsigned)f2bf(acc[2 * t + 1] * di) << 16);
    }
    *(int4*)(aggH + (size_t)node * DIM + col * 8) =
        make_int4((int)ph[0], (int)ph[1], (int)ph[2], (int)ph[3]);
  }
}

// ---------------- MFMA SAGE layer (bf16 weights) ----------------
// out = relu( aggH@WlH + xH@WrH + b ); optional fused lin3 -> y. LDS 32 KB.
__global__ __launch_bounds__(256) void sage_mfma_kernel(
    const ushort* __restrict__ aggH, const ushort* xH,
    const ushort* __restrict__ WlH, const ushort* __restrict__ WrH,
    const float* __restrict__ bias,
    const float* __restrict__ W3l, const float* __restrict__ W3r,
    ushort* __restrict__ outH, float* __restrict__ y, int N) {
  __shared__ ushort As[128 * 64];  // 16 KB
  __shared__ ushort Bs[128 * 64];  // 16 KB

  const int tid = threadIdx.x;
  const int bm = blockIdx.x * 128;
  const int wave = tid >> 6;
  const int lane = tid & 63;
  const int l15 = lane & 15;
  const int quad = lane >> 4;
  const int wm = wave >> 1;
  const int wn = wave & 1;

  f32x4 acc[4][4];
#pragma unroll
  for (int i = 0; i < 4; ++i)
#pragma unroll
    for (int j = 0; j < 4; ++j) acc[i][j] = (f32x4){0.f, 0.f, 0.f, 0.f};

  for (int g = 0; g < 4; ++g) {
    const ushort* Ap = (g < 2) ? aggH : xH;
    const ushort* Wp = (g < 2) ? WlH : WrH;
    const int kt = (g & 1) << 6;
    __syncthreads();
#pragma unroll
    for (int c = 0; c < 4; ++c) {
      int flat = c * 256 + tid;
      int row = flat >> 3;
      int kg = flat & 7;
      int swz = (kg ^ (row & 7)) << 3;
      int grow = bm + row;
      if (grow >= N) grow = N - 1;
      *(int4*)(&As[row * 64 + swz]) = *(const int4*)(Ap + (size_t)grow * DIM + kt + kg * 8);
      *(int4*)(&Bs[row * 64 + swz]) = *(const int4*)(Wp + (size_t)row * DIM + kt + kg * 8);
    }
    __syncthreads();
#pragma unroll
    for (int ks = 0; ks < 2; ++ks) {
      bf16x8 af[4], bfr[4];
      int kg = (ks << 2) + quad;
#pragma unroll
      for (int i = 0; i < 4; ++i) {
        int ar = (wm << 6) + (i << 4) + l15;
        af[i] = *(const bf16x8*)(&As[ar * 64 + ((kg ^ (ar & 7)) << 3)]);
        int br = (wn << 6) + (i << 4) + l15;
        bfr[i] = *(const bf16x8*)(&Bs[br * 64 + ((kg ^ (br & 7)) << 3)]);
      }
#pragma unroll
      for (int i = 0; i < 4; ++i)
#pragma unroll
        for (int j = 0; j < 4; ++j)
          acc[i][j] = __builtin_amdgcn_mfma_f32_16x16x32_bf16(af[i], bfr[j], acc[i][j], 0, 0, 0);
    }
  }

  __syncthreads();  // As/Bs dead; alias epilogue buffers onto As
  float* WcF = reinterpret_cast<float*>(As);        // [128][4] = 2 KB
  float* YpF = reinterpret_cast<float*>(As) + 512;  // [128][4][2] = 4 KB

  if (W3l) {
    for (int t = tid; t < 512; t += 256) {
      int col = t >> 2, c = t & 3;
      WcF[t] = (c < 2) ? W3l[col * 2 + c] : W3r[col * 2 + (c - 2)];
    }
    __syncthreads();
  }

  float bv[4];
#pragma unroll
  for (int j = 0; j < 4; ++j) bv[j] = bias[(wn << 6) + (j << 4) + l15];

#pragma unroll
  for (int i = 0; i < 4; ++i) {
#pragma unroll
    for (int r = 0; r < 4; ++r) {
      const int rowl = (wm << 6) + (i << 4) + (quad << 2) + r;
      const int grow = bm + rowl;
      float p0 = 0.f, p1 = 0.f, p2 = 0.f, p3 = 0.f;
#pragma unroll
      for (int j = 0; j < 4; ++j) {
        int col = (wn << 6) + (j << 4) + l15;
        float v = fmaxf(acc[i][j][r] + bv[j], 0.f);
        ushort h = f2bf(v);
        if (outH && grow < N) outH[(size_t)grow * DIM + col] = h;
        if (W3l) {
          float qv = bf2f(h);
          p0 += qv * WcF[col * 4 + 0];
          p1 += qv * WcF[col * 4 + 1];
          p2 += qv * WcF[col * 4 + 2];
          p3 += qv * WcF[col * 4 + 3];
        }
      }
      if (W3l) {
#pragma unroll
        for (int o = 1; o < 16; o <<= 1) {
          p0 += __shfl_xor(p0, o, 64);
          p1 += __shfl_xor(p1, o, 64);
          p2 += __shfl_xor(p2, o, 64);
          p3 += __shfl_xor(p3, o, 64);
        }
        if (l15 == 0) {
          YpF[(rowl * 4 + 0) * 2 + wn] = p0;
          YpF[(rowl * 4 + 1) * 2 + wn] = p1;
          YpF[(rowl * 4 + 2) * 2 + wn] = p2;
          YpF[(rowl * 4 + 3) * 2 + wn] = p3;
        }
      }
    }
  }

  if (W3l) {
    __syncthreads();
    for (int t = tid; t < 512; t += 256) {
      int grow = bm + (t >> 2);
      if (grow < N) y[(size_t)grow * 4 + (t & 3)] = YpF[t * 2 + 0] + YpF[t * 2 + 1];
    }
  }
}

// ---------------- layer 3: 2-dim CSR gather + bias + relu + log_softmax (offsets inline) ----------------
__global__ __launch_bounds__(256) void final3_kernel(const float* __restrict__ y,
                                                     const int* __restrict__ csr_src,
                                                     const unsigned* __restrict__ excl,
                                                     const unsigned* __restrict__ partial,
                                                     const unsigned* __restrict__ deg,
                                                     const float* __restrict__ dinv,
                                                     const float* __restrict__ b3,
                                                     float* __restrict__ out, int N) {
  int n = blockIdx.x * 256 + threadIdx.x;
  if (n >= N) return;
  unsigned beg = excl[n] + partial[n >> 8];
  unsigned end = beg + deg[n];
  float s0 = 0.f, s1 = 0.f;
  for (unsigned e = beg; e < end; ++e) {
    int s = csr_src[e];
    float2 v = *reinterpret_cast<const float2*>(&y[(size_t)s * 4]);
    s0 += v.x; s1 += v.y;
  }
  float di = dinv[n];
  float o0 = fmaxf(s0 * di + y[(size_t)n * 4 + 2] + b3[0], 0.f);
  float o1 = fmaxf(s1 * di + y[(size_t)n * 4 + 3] + b3[1], 0.f);
  float m = fmaxf(o0, o1);
  float l = m + logf(expf(o0 - m) + expf(o1 - m));
  out[n * 2 + 0] = o0 - l;
  out[n * 2 + 1] = o1 - l;
}

extern "C" void kernel_launch(void* const* d_in, const int* in_sizes, int n_in,
                              void* d_out, int out_size, void* d_ws, size_t ws_size,
                              hipStream_t stream) {
  const float* x   = (const float*)d_in[0];
  const int*   ei  = (const int*)d_in[1];
  const float* W1l = (const float*)d_in[2];
  const float* W1r = (const float*)d_in[3];
  const float* b1  = (const float*)d_in[4];
  const float* W2l = (const float*)d_in[5];
  const float* W2r = (const float*)d_in[6];
  const float* b2  = (const float*)d_in[7];
  const float* W3l = (const float*)d_in[8];
  const float* W3r = (const float*)d_in[9];
  const float* b3  = (const float*)d_in[10];

  const int N = in_sizes[0] / DIM;  // 100000
  const int E = in_sizes[1] / 2;    // 1600000
  const int* src = ei;
  const int* dst = ei + E;
  const int B = (N + 255) / 256;

  char* ws = (char*)d_ws;
  size_t off_b = 0;
  auto alloc = [&](size_t bytes) {
    void* p = ws + off_b;
    off_b = (off_b + bytes + 255) & ~(size_t)255;
    return p;
  };
  unsigned* deg     = (unsigned*)alloc((size_t)N * 4 + 4);  // +ticket word at deg[N]
  unsigned* ticket  = deg + N;
  unsigned* excl    = (unsigned*)alloc((size_t)N * 4);
  unsigned* partial = (unsigned*)alloc((size_t)B * 4);
  unsigned* rank    = (unsigned*)alloc((size_t)E * 4);
  int*      csr_src = (int*)alloc((size_t)E * 4);
  float*    dinv    = (float*)alloc((size_t)N * 4);
  ushort*   xH      = (ushort*)alloc((size_t)N * DIM * 2);
  ushort*   aggH    = (ushort*)alloc((size_t)N * DIM * 2);
  ushort*   wtabs   = (ushort*)alloc((size_t)4 * 16384 * 2);
  float*    y       = (float*)alloc((size_t)N * 4 * 4);

  // ---- fused prep: hist_rank || cast || wsplit, interleaved ----
  const int H = (E + 255) / 256;                           // 6250
  const int C = (int)(((size_t)N * DIM / 4 + 255) / 256);  // 12500
  const int third = (H > (C + 257) / 2) ? H : (C + 257) / 2;
  hipMemsetAsync(deg, 0, (size_t)N * 4 + 4, stream);  // deg + ticket
  prep_kernel<<<third * 3, 256, 0, stream>>>(dst, deg, rank, E, x, xH, (long)N * DIM,
                                             W1l, W1r, W2l, W2r, wtabs, H, C);

  // ---- fused scan (block scan + dinv + last-block partial scan) ----
  scan_fused_kernel<<<B, 256, 0, stream>>>(deg, excl, partial, dinv, ticket, N, B);

  // ---- CSR fill (offsets inline) ----
  csr_fill_kernel<<<(E + 255) / 256, 256, 0, stream>>>(src, dst, rank, excl, partial, csr_src, E);

  const ushort* W1lH = wtabs;
  const ushort* W1rH = wtabs + 16384;
  const ushort* W2lH = wtabs + 32768;
  const ushort* W2rH = wtabs + 49152;

  const int G = (N + 127) / 128;
  const int gather_grid = (N + 3) / 4;  // one wave per node

  // ---- layer 1: h1 = relu(agg@W1l + x@W1r + b1) in-place over xH ----
  gather_wave_kernel<<<gather_grid, 256, 0, stream>>>(xH, csr_src, excl, partial, deg, dinv,
                                                      aggH, N);
  sage_mfma_kernel<<<G, 256, 0, stream>>>(aggH, xH, W1lH, W1rH, b1,
                                          nullptr, nullptr, xH, nullptr, N);
  // ---- layer 2: y only (fused lin3; no h2 store) ----
  gather_wave_kernel<<<gather_grid, 256, 0, stream>>>(xH, csr_src, excl, partial, deg, dinv,
                                                      aggH, N);
  sage_mfma_kernel<<<G, 256, 0, stream>>>(aggH, xH, W2lH, W2rH, b2,
                                          W3l, W3r, nullptr, y, N);
  // ---- layer 3 ----
  final3_kernel<<<(N + 255) / 256, 256, 0, stream>>>(y, csr_src, excl, partial, deg, dinv, b3,
                                                     (float*)d_out, N);
}